// Round 7
// baseline (287.730 us; speedup 1.0000x reference)
//
#include <hip/hip_runtime.h>

#define HW 3136
#define PLANE_ROWS 3584                  // 64 lead slack + 3364 data (58x58) + 156 tail slack
#define PLANE_SHORTS (PLANE_ROWS * 16)   // per (b,cb,kh) plane: 16 shorts (32B) per row

typedef __attribute__((ext_vector_type(4))) float f32x4;
typedef __attribute__((ext_vector_type(16))) float f32x16;
typedef __attribute__((ext_vector_type(8))) short s16x8;
typedef __attribute__((ext_vector_type(8))) __bf16 bf16x8;
typedef unsigned long long ull;
typedef __attribute__((ext_vector_type(2))) ull u64x2;

// ws layout (bytes)
#define XLEV_BYTES ((size_t)512 * PLANE_SHORTS * 2UL)   // 64b x 4cb x 2kh planes = 58.72MB
#define WLEV_OFF   XLEV_BYTES
#define WLEV_BYTES (589824UL * 2UL)
#define POOL_OFF   (WLEV_OFF + WLEV_BYTES)
#define POOL_BYTES (8192UL * 8UL)
#define PAR_OFF    (POOL_OFF + POOL_BYTES)

__device__ __forceinline__ unsigned short f2bf_bits(float f) {
    return (unsigned short)(__float_as_uint(f) >> 16);
}

__device__ __forceinline__ void glds16(const void* g, void* l) {
    __builtin_amdgcn_global_load_lds((const __attribute__((address_space(1))) void*)g,
                                     (__attribute__((address_space(3))) void*)l, 16, 0, 0);
}

// ---------------- fused prep: pool (2048 blk) + wq (288 blk) + zeropad (256 blk) ----------------
__global__ void prep_kernel(const float* __restrict__ x, const float* __restrict__ w,
                            const float* __restrict__ alpha_w,
                            double* __restrict__ pooled, unsigned short* __restrict__ wlev,
                            unsigned short* __restrict__ xlev) {
    int bid = blockIdx.x;
    int t = threadIdx.x;
    if (bid < 2048) {
        int row = bid * 4 + (t >> 6);
        int lane = t & 63;
        const float4* xr = (const float4*)(x + (size_t)row * HW);
        double s = 0.0;
        for (int i = lane; i < 784; i += 64) {
            float4 v = xr[i];
            s += (double)v.x + (double)v.y + (double)v.z + (double)v.w;
        }
        for (int off = 32; off; off >>= 1) s += __shfl_down(s, off, 64);
        if (lane == 0) pooled[row] = s / 3136.0;
    } else if (bid < 2336) {
        // wq -> wlev [k][tap][cb][kh][o][2][8] : dst short-offset = id*8
        int id = (bid - 2048) * 256 + t;
        int hh = id & 1;
        int o  = (id >> 1) & 127;
        int kh = (id >> 8) & 1;
        int cb = (id >> 9) & 3;
        int rest = id >> 11;            // k*9 + tap
        int tap = rest % 9, k = rest / 9;
        float Qpw = (float)((1 << (k + 1)) - 1);
        float Qnw = -(float)(1 << (k + 1));
        float g_w = __fdiv_rn(1.0f, __fsqrt_rn(__fmul_rn(589824.0f, Qpw)));
        float tw  = __fmul_rn(alpha_w[k], g_w);
        float aw  = __fadd_rn(__fsub_rn(alpha_w[k], tw), tw);
        const float* wsrc = w + ((size_t)(k * 128 + o) * 128 + cb * 32 + kh * 16 + hh * 8) * 9 + tap;
        s16x8 outv;
        for (int j = 0; j < 8; j++) {
            float lv = rintf(fminf(fmaxf(__fdiv_rn(wsrc[j * 9], aw), Qnw), Qpw));
            outv[j] = (short)f2bf_bits(lv);
        }
        *(s16x8*)(wlev + (size_t)id * 8) = outv;
    } else {
        // zeropad data borders of both kh planes of (b,cb)
        int plane = bid - 2336;   // 0..255 = b*4+cb
        unsigned short* pl = xlev + (size_t)(plane * 2) * PLANE_SHORTS;
        for (int i = t; i < 228 * 8; i += 256) {
            int cell = i >> 3, d = i & 7;
            int row;
            if (cell < 58)       row = cell;                        // ph=0
            else if (cell < 116) row = 3306 + (cell - 58);          // ph=57
            else if (cell < 172) row = (cell - 115) * 58;           // pw=0
            else                 row = (cell - 171) * 58 + 57;      // pw=57
            ((unsigned int*)(pl + (size_t)(64 + row) * 16))[d] = 0u;
            ((unsigned int*)(pl + PLANE_SHORTS + (size_t)(64 + row) * 16))[d] = 0u;
        }
    }
}

// ---------------- gate: 64 blocks (one per batch), 64 threads ----------------
__global__ void gate_kernel(const double* __restrict__ pooled,
                            const float* __restrict__ fc1, const float* __restrict__ fc2,
                            const float* __restrict__ fc2b, const float* __restrict__ alpha_w,
                            const float* __restrict__ alpha_a,
                            float* __restrict__ params, float* __restrict__ raw_out) {
    int b = blockIdx.x;
    int t = threadIdx.x;
    __shared__ double pl[128];
    __shared__ double hsh[33];
    __shared__ float rawsh[4];
    pl[t]      = pooled[b * 128 + t];
    pl[t + 64] = pooled[b * 128 + 64 + t];
    __syncthreads();
    if (t < 33) {
        double s = 0.0;
        for (int c = 0; c < 128; c++) s += pl[c] * (double)fc1[t * 128 + c];
        hsh[t] = s > 0.0 ? s : 0.0;
    }
    __syncthreads();
    if (t < 4) {
        double s = (double)fc2b[t];
        for (int j = 0; j < 33; j++) s += hsh[j] * (double)fc2[t * 33 + j];
        float r = (float)s;
        rawsh[t] = r;
        raw_out[b * 4 + t] = r;
    }
    __syncthreads();
    if (t == 0) {
        float raw[4];
        for (int k = 0; k < 4; k++) raw[k] = rawsh[k];
        int kb = 0; float mx = raw[0];
        for (int k = 1; k < 4; k++) if (raw[k] > mx) { mx = raw[k]; kb = k; }
        float z[4], m = -1e30f;
        for (int k = 0; k < 4; k++) { z[k] = __fdiv_rn(raw[k], 34.0f); m = fmaxf(m, z[k]); }
        float p[4], sum = 0.0f;
        for (int k = 0; k < 4; k++) {
            p[k] = (float)exp((double)__fsub_rn(z[k], m));
            sum = __fadd_rn(sum, p[k]);
        }
        float s_k   = __fdiv_rn(p[kb], sum);
        float attn1 = __fadd_rn(__fsub_rn(1.0f, s_k), s_k);
        float Qp    = (float)((1 << (kb + 2)) - 1);
        float rQp   = __fmul_rn(attn1, Qp);
        float r_al  = __fmul_rn(attn1, alpha_a[kb]);
        float g_a   = __fdiv_rn(1.0f, __fsqrt_rn(__fmul_rn(401408.0f, rQp)));
        float ta    = __fmul_rn(r_al, g_a);
        float a     = __fadd_rn(__fsub_rn(r_al, ta), ta);
        float Qpw   = (float)((1 << (kb + 1)) - 1);
        float g_w   = __fdiv_rn(1.0f, __fsqrt_rn(__fmul_rn(589824.0f, Qpw)));
        float tw    = __fmul_rn(alpha_w[kb], g_w);
        float aw    = __fadd_rn(__fsub_rn(alpha_w[kb], tw), tw);
        params[b * 8 + 0] = __int_as_float(kb);
        params[b * 8 + 1] = a;
        params[b * 8 + 2] = rQp;
        params[b * 8 + 3] = attn1;
        params[b * 8 + 4] = __fmul_rn(a, aw);
    }
}

// ---- x quant + transpose -> swizzled padded kh-split planes [b][cb][kh][64+r][16sh] ----
__global__ void xq_kernel(const float* __restrict__ x, const float* __restrict__ params,
                          unsigned short* __restrict__ xlev) {
    __shared__ unsigned short lds[64 * 136];
    int b = blockIdx.y, tile = blockIdx.x;
    int p0 = tile * 64;
    float a = params[b * 8 + 1], rQp = params[b * 8 + 2];
    const float* xb = x + (size_t)b * 401408;
    int t = threadIdx.x;
    int cc = t >> 4;
    int p4 = (t & 15) * 4;
    for (int j = 0; j < 8; j++) {
        int c = cc * 8 + j;
        float4 v = *(const float4*)(xb + (size_t)c * HW + p0 + p4);
        float q0 = rintf(fminf(fmaxf(__fdiv_rn(v.x, a), 0.0f), rQp));
        float q1 = rintf(fminf(fmaxf(__fdiv_rn(v.y, a), 0.0f), rQp));
        float q2 = rintf(fminf(fmaxf(__fdiv_rn(v.z, a), 0.0f), rQp));
        float q3 = rintf(fminf(fmaxf(__fdiv_rn(v.w, a), 0.0f), rQp));
        lds[(p4 + 0) * 136 + c] = f2bf_bits(q0);
        lds[(p4 + 1) * 136 + c] = f2bf_bits(q1);
        lds[(p4 + 2) * 136 + c] = f2bf_bits(q2);
        lds[(p4 + 3) * 136 + c] = f2bf_bits(q3);
    }
    __syncthreads();
    int p = t >> 2, seg = t & 3;          // seg = kh*2 + half
    int kh = seg >> 1, hf = seg & 1;
    int pix = p0 + p;
    int r = pix + 2 * (pix / 56) + 59;    // data row (h+1)*58 + (w+1)
    int swz = (r >> 2) & 1;               // bit2 of plane row (lead 64 doesn't change it)
    const unsigned short* s = &lds[p * 136];
    unsigned short* dstb = xlev + (size_t)(b * 8 + kh) * PLANE_SHORTS
                          + (size_t)(64 + r) * 16 + ((hf ^ swz) << 3);
    for (int cb = 0; cb < 4; cb++) {
        *(u64x2*)(dstb + (size_t)(cb * 2) * PLANE_SHORTS) = *(const u64x2*)(s + cb * 32 + seg * 8);
    }
}

// ---- conv: 128o x 128 padded-rows, 2x2 waves (A reuse 2, B reuse 2), swizzled LDS ----
__launch_bounds__(256)
__global__ void conv_kernel(const unsigned short* __restrict__ xlev,
                            const unsigned short* __restrict__ wlev,
                            const float* __restrict__ params,
                            const float* __restrict__ bias,
                            float* __restrict__ out) {
    __shared__ unsigned short Bl[2][8192];    // [buf][kh*4096 + localrow*16], 2 x 16KB
    int lid = blockIdx.x + blockIdx.y * 27;   // grid (27,64) = 1728
    int xcd = lid & 7, s = lid >> 3;          // 216 slots per XCD
    int b = xcd * 8 + s / 27, tile = s % 27;
    int kb = __float_as_int(params[b * 8 + 0]);
    float scale = params[b * 8 + 4], attn1 = params[b * 8 + 3];
    const unsigned short* xb = xlev + (size_t)(b * 8) * PLANE_SHORTS;
    const unsigned short* wb = wlev + (size_t)kb * 147456;
    int tid = threadIdx.x, lane = tid & 63, wv = tid >> 6;
    int wm = wv >> 1, wn = wv & 1;
    int l32 = lane & 31, h = lane >> 5;

    int lam[2], aoff[2];
    #pragma unroll
    for (int nt = 0; nt < 2; nt++) lam[nt] = wn * 64 + nt * 32 + l32;
    #pragma unroll
    for (int mt = 0; mt < 2; mt++) aoff[mt] = (wm * 64 + mt * 32 + l32) * 16 + h * 8;

    f32x16 acc[2][2] = {};

    size_t srow = (size_t)tile * 128 * 16;    // stage base (shorts) within each plane

    {   // stage cb=0
        const unsigned short* g = xb + srow;
        #pragma unroll
        for (int kp = 0; kp < 4; kp++)
            glds16(g + (size_t)(kp >> 1) * PLANE_SHORTS + (kp & 1) * 2048 + tid * 8,
                   &Bl[0][(kp >> 1) * 4096 + (kp & 1) * 2048 + wv * 512]);
    }

    #pragma unroll
    for (int cb = 0; cb < 4; cb++) {
        __syncthreads();
        if (cb < 3) {
            const unsigned short* g = xb + (size_t)((cb + 1) * 2) * PLANE_SHORTS + srow;
            #pragma unroll
            for (int kp = 0; kp < 4; kp++)
                glds16(g + (size_t)(kp >> 1) * PLANE_SHORTS + (kp & 1) * 2048 + tid * 8,
                       &Bl[(cb + 1) & 1][(kp >> 1) * 4096 + (kp & 1) * 2048 + wv * 512]);
        }
        const unsigned short* Bc = &Bl[cb & 1][0];
        const unsigned short* wcb = wb + cb * 4096;
        #pragma unroll
        for (int kh = 0; kh < 2; kh++) {
            const unsigned short* wkh = wcb + kh * 2048;
            const unsigned short* Bk = Bc + kh * 4096;
            #pragma unroll
            for (int t9 = 0; t9 < 9; t9++) {
                int dlt = (t9 / 3) * 58 + (t9 % 3) - 59;
                const unsigned short* ga = wkh + t9 * 16384;
                s16x8 af0 = *(const s16x8*)(ga + aoff[0]);
                s16x8 af1 = *(const s16x8*)(ga + aoff[1]);
                int r0 = lam[0] + dlt, r1 = lam[1] + dlt;
                s16x8 bf0 = *(const s16x8*)(Bk + (r0 + 64) * 16 + ((h ^ ((r0 >> 2) & 1)) << 3));
                s16x8 bf1 = *(const s16x8*)(Bk + (r1 + 64) * 16 + ((h ^ ((r1 >> 2) & 1)) << 3));
                acc[0][0] = __builtin_amdgcn_mfma_f32_32x32x16_bf16(
                    __builtin_bit_cast(bf16x8, af0), __builtin_bit_cast(bf16x8, bf0), acc[0][0], 0, 0, 0);
                acc[1][0] = __builtin_amdgcn_mfma_f32_32x32x16_bf16(
                    __builtin_bit_cast(bf16x8, af1), __builtin_bit_cast(bf16x8, bf0), acc[1][0], 0, 0, 0);
                acc[0][1] = __builtin_amdgcn_mfma_f32_32x32x16_bf16(
                    __builtin_bit_cast(bf16x8, af0), __builtin_bit_cast(bf16x8, bf1), acc[0][1], 0, 0, 0);
                acc[1][1] = __builtin_amdgcn_mfma_f32_32x32x16_bf16(
                    __builtin_bit_cast(bf16x8, af1), __builtin_bit_cast(bf16x8, bf1), acc[1][1], 0, 0, 0);
            }
        }
    }

    // epilogue with border/overrun masking
    const float* bias_k = bias + kb * 128;
    int pv[2], pp[2];
    #pragma unroll
    for (int nt = 0; nt < 2; nt++) {
        int prd = tile * 128 + lam[nt];        // padded-image row index (data-relative)
        int ph = prd / 58, pw = prd - ph * 58;
        pv[nt] = (ph >= 1) && (ph <= 56) && (pw >= 1) && (pw <= 56);
        pp[nt] = (ph - 1) * 56 + pw - 1;
    }
    #pragma unroll
    for (int mt = 0; mt < 2; mt++) {
        #pragma unroll
        for (int reg = 0; reg < 16; reg++) {
            int o = wm * 64 + mt * 32 + 4 * h + (reg & 3) + 8 * (reg >> 2);
            float bt = __fmul_rn(attn1, bias_k[o]);
            float* orow = out + ((size_t)b * 128 + o) * 3136;
            #pragma unroll
            for (int nt = 0; nt < 2; nt++)
                if (pv[nt])
                    orow[pp[nt]] = __fadd_rn(__fmul_rn(scale, acc[mt][nt][reg]), bt);
        }
    }
}

extern "C" void kernel_launch(void* const* d_in, const int* in_sizes, int n_in,
                              void* d_out, int out_size, void* d_ws, size_t ws_size,
                              hipStream_t stream) {
    const float* x        = (const float*)d_in[0];
    const float* fc1_w    = (const float*)d_in[1];
    const float* fc2_w    = (const float*)d_in[2];
    const float* fc2_b    = (const float*)d_in[3];
    const float* alpha_w  = (const float*)d_in[4];
    const float* alpha_a  = (const float*)d_in[5];
    const float* weight   = (const float*)d_in[6];
    const float* bias     = (const float*)d_in[7];
    float* out = (float*)d_out;

    char* ws = (char*)d_ws;
    unsigned short* xlev = (unsigned short*)(ws);
    unsigned short* wlev = (unsigned short*)(ws + WLEV_OFF);
    double* pooled       = (double*)(ws + POOL_OFF);
    float* par           = (float*)(ws + PAR_OFF);

    hipLaunchKernelGGL(prep_kernel, dim3(2592), dim3(256), 0, stream,
                       x, weight, alpha_w, pooled, wlev, xlev);
    hipLaunchKernelGGL(gate_kernel, dim3(64), dim3(64), 0, stream,
                       pooled, fc1_w, fc2_w, fc2_b, alpha_w, alpha_a, par, out + 25690112);
    hipLaunchKernelGGL(xq_kernel, dim3(49, 64), dim3(256), 0, stream, x, par, xlev);
    hipLaunchKernelGGL(conv_kernel, dim3(27, 64), dim3(256), 0, stream, xlev, wlev, par, bias, out);
}

// Round 8
// 280.810 us; speedup vs baseline: 1.0246x; 1.0246x over previous
//
#include <hip/hip_runtime.h>

#define HW 3136
#define PLANE_ROWS 3584                  // 64 lead slack + 3364 data (58x58) + 156 tail slack
#define PLANE_BYTES (PLANE_ROWS * 32)    // per (b,cb) plane, 32 i8 channels per row

typedef __attribute__((ext_vector_type(4))) int i32x4;
typedef __attribute__((ext_vector_type(16))) int i32x16;
typedef __attribute__((ext_vector_type(16))) char c8x16;
typedef unsigned long long ull;
typedef __attribute__((ext_vector_type(2))) ull u64x2;

// ws layout (bytes)
#define XLEV_BYTES ((size_t)256 * PLANE_BYTES)   // 64b x 4cb planes = 29.36MB
#define WLEV_OFF   XLEV_BYTES
#define WLEV_BYTES (589824UL)                    // 4k x 4cb x 9tap x 128o x 32 i8
#define POOL_OFF   (WLEV_OFF + WLEV_BYTES)
#define POOL_BYTES (8192UL * 8UL)
#define PAR_OFF    (POOL_OFF + POOL_BYTES)

__device__ __forceinline__ void glds16(const void* g, void* l) {
    __builtin_amdgcn_global_load_lds((const __attribute__((address_space(1))) void*)g,
                                     (__attribute__((address_space(3))) void*)l, 16, 0, 0);
}

// ---------------- fused prep: pool (2048 blk) + wq (144 blk) + zeropad (256 blk) ----------------
__global__ void prep_kernel(const float* __restrict__ x, const float* __restrict__ w,
                            const float* __restrict__ alpha_w,
                            double* __restrict__ pooled, signed char* __restrict__ wlev,
                            signed char* __restrict__ xlev) {
    int bid = blockIdx.x;
    int t = threadIdx.x;
    if (bid < 2048) {
        int row = bid * 4 + (t >> 6);
        int lane = t & 63;
        const float4* xr = (const float4*)(x + (size_t)row * HW);
        double s = 0.0;
        for (int i = lane; i < 784; i += 64) {
            float4 v = xr[i];
            s += (double)v.x + (double)v.y + (double)v.z + (double)v.w;
        }
        for (int off = 32; off; off >>= 1) s += __shfl_down(s, off, 64);
        if (lane == 0) pooled[row] = s / 3136.0;
    } else if (bid < 2192) {
        // wq -> wlev [k][cb][tap][o][2hh][16 i8]
        int id = (bid - 2048) * 256 + t;     // 0..36863
        int k    = id / 9216;
        int rem  = id - k * 9216;
        int cb   = rem / 2304;
        int rem2 = rem - cb * 2304;
        int tap  = rem2 >> 8;
        int o    = (rem2 >> 1) & 127;
        int hh   = rem2 & 1;
        float Qpw = (float)((1 << (k + 1)) - 1);
        float Qnw = -(float)(1 << (k + 1));
        float g_w = __fdiv_rn(1.0f, __fsqrt_rn(__fmul_rn(589824.0f, Qpw)));
        float tw  = __fmul_rn(alpha_w[k], g_w);
        float aw  = __fadd_rn(__fsub_rn(alpha_w[k], tw), tw);
        const float* wsrc = w + ((size_t)(k * 128 + o) * 128 + cb * 32 + hh * 16) * 9 + tap;
        c8x16 v;
        for (int j = 0; j < 16; j++) {
            float lv = rintf(fminf(fmaxf(__fdiv_rn(wsrc[j * 9], aw), Qnw), Qpw));
            v[j] = (char)(int)lv;
        }
        *(c8x16*)(wlev + (size_t)id * 16) = v;
    } else {
        // zeropad data borders of (b,cb) plane
        int plane = bid - 2192;   // 0..255 = b*4+cb
        signed char* pl = xlev + (size_t)plane * PLANE_BYTES;
        u64x2 z = {0, 0};
        for (int i = t; i < 456; i += 256) {
            int cell = i >> 1;
            int row;
            if (cell < 58)       row = cell;                        // ph=0
            else if (cell < 116) row = 3306 + (cell - 58);          // ph=57
            else if (cell < 172) row = (cell - 115) * 58;           // pw=0
            else                 row = (cell - 171) * 58 + 57;      // pw=57
            *(u64x2*)(pl + (size_t)(64 + row) * 32 + (i & 1) * 16) = z;
        }
    }
}

// ---------------- gate: 64 blocks (one per batch), 64 threads ----------------
__global__ void gate_kernel(const double* __restrict__ pooled,
                            const float* __restrict__ fc1, const float* __restrict__ fc2,
                            const float* __restrict__ fc2b, const float* __restrict__ alpha_w,
                            const float* __restrict__ alpha_a,
                            float* __restrict__ params, float* __restrict__ raw_out) {
    int b = blockIdx.x;
    int t = threadIdx.x;
    __shared__ double pl[128];
    __shared__ double hsh[33];
    __shared__ float rawsh[4];
    pl[t]      = pooled[b * 128 + t];
    pl[t + 64] = pooled[b * 128 + 64 + t];
    __syncthreads();
    if (t < 33) {
        double s = 0.0;
        for (int c = 0; c < 128; c++) s += pl[c] * (double)fc1[t * 128 + c];
        hsh[t] = s > 0.0 ? s : 0.0;
    }
    __syncthreads();
    if (t < 4) {
        double s = (double)fc2b[t];
        for (int j = 0; j < 33; j++) s += hsh[j] * (double)fc2[t * 33 + j];
        float r = (float)s;
        rawsh[t] = r;
        raw_out[b * 4 + t] = r;
    }
    __syncthreads();
    if (t == 0) {
        float raw[4];
        for (int k = 0; k < 4; k++) raw[k] = rawsh[k];
        int kb = 0; float mx = raw[0];
        for (int k = 1; k < 4; k++) if (raw[k] > mx) { mx = raw[k]; kb = k; }
        float z[4], m = -1e30f;
        for (int k = 0; k < 4; k++) { z[k] = __fdiv_rn(raw[k], 34.0f); m = fmaxf(m, z[k]); }
        float p[4], sum = 0.0f;
        for (int k = 0; k < 4; k++) {
            p[k] = (float)exp((double)__fsub_rn(z[k], m));
            sum = __fadd_rn(sum, p[k]);
        }
        float s_k   = __fdiv_rn(p[kb], sum);
        float attn1 = __fadd_rn(__fsub_rn(1.0f, s_k), s_k);
        float Qp    = (float)((1 << (kb + 2)) - 1);
        float rQp   = __fmul_rn(attn1, Qp);
        float r_al  = __fmul_rn(attn1, alpha_a[kb]);
        float g_a   = __fdiv_rn(1.0f, __fsqrt_rn(__fmul_rn(401408.0f, rQp)));
        float ta    = __fmul_rn(r_al, g_a);
        float a     = __fadd_rn(__fsub_rn(r_al, ta), ta);
        float Qpw   = (float)((1 << (kb + 1)) - 1);
        float g_w   = __fdiv_rn(1.0f, __fsqrt_rn(__fmul_rn(589824.0f, Qpw)));
        float tw    = __fmul_rn(alpha_w[kb], g_w);
        float aw    = __fadd_rn(__fsub_rn(alpha_w[kb], tw), tw);
        params[b * 8 + 0] = __int_as_float(kb);
        params[b * 8 + 1] = a;
        params[b * 8 + 2] = rQp;
        params[b * 8 + 3] = attn1;
        params[b * 8 + 4] = __fmul_rn(a, aw);
    }
}

// ---- x quant + transpose -> swizzled padded i8 planes [b][cb][64+d][32 i8] ----
__global__ void xq_kernel(const float* __restrict__ x, const float* __restrict__ params,
                          signed char* __restrict__ xlev) {
    __shared__ __align__(16) unsigned char lds[64 * 144];
    int b = blockIdx.y, tile = blockIdx.x;
    int p0 = tile * 64;
    float a = params[b * 8 + 1], rQp = params[b * 8 + 2];
    const float* xb = x + (size_t)b * 401408;
    int t = threadIdx.x;
    int cc = t >> 4;
    int p4 = (t & 15) * 4;
    for (int j = 0; j < 8; j++) {
        int c = cc * 8 + j;
        float4 v = *(const float4*)(xb + (size_t)c * HW + p0 + p4);
        lds[(p4 + 0) * 144 + c] = (unsigned char)(int)rintf(fminf(fmaxf(__fdiv_rn(v.x, a), 0.0f), rQp));
        lds[(p4 + 1) * 144 + c] = (unsigned char)(int)rintf(fminf(fmaxf(__fdiv_rn(v.y, a), 0.0f), rQp));
        lds[(p4 + 2) * 144 + c] = (unsigned char)(int)rintf(fminf(fmaxf(__fdiv_rn(v.z, a), 0.0f), rQp));
        lds[(p4 + 3) * 144 + c] = (unsigned char)(int)rintf(fminf(fmaxf(__fdiv_rn(v.w, a), 0.0f), rQp));
    }
    __syncthreads();
    int p = t >> 2, cb = t & 3;
    int pix = p0 + p;
    int d = pix + 2 * (pix / 56) + 59;    // data row (h+1)*58 + (w+1)
    int swz = (d >> 2) & 1;
    const unsigned char* s = &lds[p * 144 + cb * 32];
    signed char* dst = xlev + (size_t)(b * 4 + cb) * PLANE_BYTES + (size_t)(64 + d) * 32;
    *(u64x2*)(dst + ((0 ^ swz) << 4)) = *(const u64x2*)(s);
    *(u64x2*)(dst + ((1 ^ swz) << 4)) = *(const u64x2*)(s + 16);
}

// ---- conv: 128o x 128 padded-rows, i8 32x32x32 MFMA, A preloaded/cb, B swizzled LDS dbuf ----
__launch_bounds__(256)
__global__ void conv_kernel(const signed char* __restrict__ xlev,
                            const signed char* __restrict__ wlev,
                            const float* __restrict__ params,
                            const float* __restrict__ bias,
                            float* __restrict__ out) {
    __shared__ __align__(16) signed char Bl[2][8192];   // 2 x 8KB: 256 halo rows x 32 i8
    int lid = blockIdx.x + blockIdx.y * 27;   // grid (27,64) = 1728
    int xcd = lid & 7, s = lid >> 3;
    int b = xcd * 8 + s / 27, tile = s % 27;
    int kb = __float_as_int(params[b * 8 + 0]);
    float scale = params[b * 8 + 4], attn1 = params[b * 8 + 3];
    const signed char* xb = xlev + (size_t)(b * 4) * PLANE_BYTES;
    const signed char* wk = wlev + (size_t)kb * 147456;   // [cb][tap][o][32]
    int tid = threadIdx.x, lane = tid & 63, wv = tid >> 6;
    int wm = wv >> 1, wn = wv & 1;
    int l32 = lane & 31, h = lane >> 5;

    int lam0 = wn * 64 + l32, lam1 = lam0 + 32;
    int aoff0 = (wm * 64 + l32) * 32 + h * 16, aoff1 = aoff0 + 1024;

    i32x16 acc[2][2] = {};

    const signed char* g0 = xb + (size_t)tile * 4096;   // stage base (256 rows x 32B)

    // stage cb=0 (8KB = 2 chunks)
    glds16(g0 + tid * 16, &Bl[0][wv * 1024]);
    glds16(g0 + 4096 + tid * 16, &Bl[0][4096 + wv * 1024]);

    #pragma unroll
    for (int cb = 0; cb < 4; cb++) {
        // A-frags for this cb -> registers (issued before barrier; drained by it)
        const signed char* wcb = wk + cb * 36864;
        i32x4 af0[9], af1[9];
        #pragma unroll
        for (int t9 = 0; t9 < 9; t9++) {
            af0[t9] = *(const i32x4*)(wcb + t9 * 4096 + aoff0);
            af1[t9] = *(const i32x4*)(wcb + t9 * 4096 + aoff1);
        }
        __syncthreads();
        if (cb < 3) {
            const signed char* gn = g0 + (size_t)(cb + 1) * PLANE_BYTES;
            glds16(gn + tid * 16, &Bl[(cb + 1) & 1][wv * 1024]);
            glds16(gn + 4096 + tid * 16, &Bl[(cb + 1) & 1][4096 + wv * 1024]);
        }
        const signed char* Bc = &Bl[cb & 1][0];
        #pragma unroll
        for (int t9 = 0; t9 < 9; t9++) {
            int dlt = (t9 / 3) * 58 + (t9 % 3) - 59;
            int r0 = lam0 + dlt, r1 = lam1 + dlt;
            i32x4 bf0 = *(const i32x4*)(Bc + (r0 + 64) * 32 + ((h ^ ((r0 >> 2) & 1)) << 4));
            i32x4 bf1 = *(const i32x4*)(Bc + (r1 + 64) * 32 + ((h ^ ((r1 >> 2) & 1)) << 4));
            acc[0][0] = __builtin_amdgcn_mfma_i32_32x32x32_i8(af0[t9], bf0, acc[0][0], 0, 0, 0);
            acc[1][0] = __builtin_amdgcn_mfma_i32_32x32x32_i8(af1[t9], bf0, acc[1][0], 0, 0, 0);
            acc[0][1] = __builtin_amdgcn_mfma_i32_32x32x32_i8(af0[t9], bf1, acc[0][1], 0, 0, 0);
            acc[1][1] = __builtin_amdgcn_mfma_i32_32x32x32_i8(af1[t9], bf1, acc[1][1], 0, 0, 0);
        }
    }

    // epilogue with border/overrun masking; float(acc) exact, scale math unchanged
    const float* bias_k = bias + kb * 128;
    int pv[2], pp[2], lam[2] = {lam0, lam1};
    #pragma unroll
    for (int nt = 0; nt < 2; nt++) {
        int prd = tile * 128 + lam[nt];
        int ph = prd / 58, pw = prd - ph * 58;
        pv[nt] = (ph >= 1) && (ph <= 56) && (pw >= 1) && (pw <= 56);
        pp[nt] = (ph - 1) * 56 + pw - 1;
    }
    #pragma unroll
    for (int mt = 0; mt < 2; mt++) {
        #pragma unroll
        for (int reg = 0; reg < 16; reg++) {
            int o = wm * 64 + mt * 32 + 4 * h + (reg & 3) + 8 * (reg >> 2);
            float bt = __fmul_rn(attn1, bias_k[o]);
            float* orow = out + ((size_t)b * 128 + o) * 3136;
            #pragma unroll
            for (int nt = 0; nt < 2; nt++)
                if (pv[nt])
                    orow[pp[nt]] = __fadd_rn(__fmul_rn(scale, (float)acc[mt][nt][reg]), bt);
        }
    }
}

extern "C" void kernel_launch(void* const* d_in, const int* in_sizes, int n_in,
                              void* d_out, int out_size, void* d_ws, size_t ws_size,
                              hipStream_t stream) {
    const float* x        = (const float*)d_in[0];
    const float* fc1_w    = (const float*)d_in[1];
    const float* fc2_w    = (const float*)d_in[2];
    const float* fc2_b    = (const float*)d_in[3];
    const float* alpha_w  = (const float*)d_in[4];
    const float* alpha_a  = (const float*)d_in[5];
    const float* weight   = (const float*)d_in[6];
    const float* bias     = (const float*)d_in[7];
    float* out = (float*)d_out;

    char* ws = (char*)d_ws;
    signed char* xlev = (signed char*)(ws);
    signed char* wlev = (signed char*)(ws + WLEV_OFF);
    double* pooled    = (double*)(ws + POOL_OFF);
    float* par        = (float*)(ws + PAR_OFF);

    hipLaunchKernelGGL(prep_kernel, dim3(2448), dim3(256), 0, stream,
                       x, weight, alpha_w, pooled, wlev, xlev);
    hipLaunchKernelGGL(gate_kernel, dim3(64), dim3(64), 0, stream,
                       pooled, fc1_w, fc2_w, fc2_b, alpha_w, alpha_a, par, out + 25690112);
    hipLaunchKernelGGL(xq_kernel, dim3(49, 64), dim3(256), 0, stream, x, par, xlev);
    hipLaunchKernelGGL(conv_kernel, dim3(27, 64), dim3(256), 0, stream, xlev, wlev, par, bias, out);
}